// Round 4
// baseline (130.521 us; speedup 1.0000x reference)
//
#include <hip/hip_runtime.h>
#include <hip/hip_bf16.h>
#include <cstdint>
#include <cstddef>

// ---------------------------------------------------------------------------
// ThreeLayerFCModel: out = relu(relu(relu(x@w0^T+b0)@(w1*m1)^T+b1)@(w2*m2)^T+b2)
// B=16384, dims 1024. Round 4: even per-phase read spread (10/4/4/6) with
// 1-phase register lookahead for Q0/b0 across the tile boundary; counted
// boundary wait moved to ph2-end (vmcnt(4)); layer-3 f32 epilogue LDS-restaged.
// ---------------------------------------------------------------------------

typedef __bf16 bf16x8 __attribute__((ext_vector_type(8)));
typedef float  f32x4  __attribute__((ext_vector_type(4)));

#define AS1 __attribute__((address_space(1)))
#define AS3 __attribute__((address_space(3)))

__device__ __forceinline__ void gload_lds16(const void* g, void* l) {
    __builtin_amdgcn_global_load_lds((const AS1 void*)g, (AS3 void*)l, 16, 0, 0);
}

// ---------------- mask dtype detection (uint8 / int32 / f32) ----------------
__global__ void detect_mask(const unsigned char* __restrict__ m, int* __restrict__ flag) {
    const int t = threadIdx.x;  // 64
    int or1 = 0, or3 = 0;
    for (int e = t; e < 256; e += 64) { or1 |= m[e * 4 + 1]; or3 |= m[e * 4 + 3]; }
    unsigned long long b1 = __ballot(or1 != 0);
    unsigned long long b3 = __ballot(or3 != 0);
    if (t == 0) *flag = b1 ? 1 : (b3 ? 2 : 0);
}

// ---------------- fused prep: cvt x->bf16 + 3x (w*mask)->bf16 ---------------
__device__ __forceinline__ void prep_body(const float* __restrict__ w,
                                          const void* __restrict__ mask, int mode,
                                          __bf16* __restrict__ out, long i) {
    float4 a = *reinterpret_cast<const float4*>(w + i);
    float4 b = *reinterpret_cast<const float4*>(w + i + 4);
    float v[8] = {a.x, a.y, a.z, a.w, b.x, b.y, b.z, b.w};
    if (mask) {
        if (mode == 1) {
            const unsigned char* mp = (const unsigned char*)mask;
            #pragma unroll
            for (int j = 0; j < 8; ++j) v[j] = mp[i + j] ? v[j] : 0.f;
        } else if (mode == 0) {
            const int* mp = (const int*)mask;
            #pragma unroll
            for (int j = 0; j < 8; ++j) v[j] = mp[i + j] ? v[j] : 0.f;
        } else {
            const float* mp = (const float*)mask;
            #pragma unroll
            for (int j = 0; j < 8; ++j) v[j] = (mp[i + j] != 0.f) ? v[j] : 0.f;
        }
    }
    bf16x8 o;
    #pragma unroll
    for (int j = 0; j < 8; ++j) o[j] = (__bf16)v[j];
    *reinterpret_cast<bf16x8*>(out + i) = o;
}

__global__ void prep_all(const float* __restrict__ x, __bf16* __restrict__ xb,
                         const float* __restrict__ w0, const float* __restrict__ w1,
                         const float* __restrict__ w2,
                         const void* __restrict__ m1, const void* __restrict__ m2,
                         const int* __restrict__ flag,
                         __bf16* __restrict__ w0b, __bf16* __restrict__ w1b,
                         __bf16* __restrict__ w2b) {
    const int bid = blockIdx.x;
    if (bid < 8192) {  // x -> bf16 (16M elems)
        long i = ((long)bid * blockDim.x + threadIdx.x) * 8;
        float4 a = *reinterpret_cast<const float4*>(x + i);
        float4 b = *reinterpret_cast<const float4*>(x + i + 4);
        bf16x8 o;
        o[0] = (__bf16)a.x; o[1] = (__bf16)a.y; o[2] = (__bf16)a.z; o[3] = (__bf16)a.w;
        o[4] = (__bf16)b.x; o[5] = (__bf16)b.y; o[6] = (__bf16)b.z; o[7] = (__bf16)b.w;
        *reinterpret_cast<bf16x8*>(xb + i) = o;
    } else {
        const int q = bid - 8192, wi = q >> 9, sub = q & 511;
        long i = ((long)sub * blockDim.x + threadIdx.x) * 8;
        const int mode = *flag;
        if (wi == 0)      prep_body(w0, nullptr, mode, w0b, i);
        else if (wi == 1) prep_body(w1, m1,      mode, w1b, i);
        else              prep_body(w2, m2,      mode, w2b, i);
    }
}

// ---------------------------------------------------------------------------
// 256x256-tile GEMM: C = relu(A[16384,1024] * W[1024,1024]^T + bias)
// 512 thr = 8 waves (2 row x 4 col), per-wave 128x64 out, BK=64, 16 K-tiles.
// LDS 128 KiB: A/B each [2 dbuf][256 rows][64 k] bf16, XOR-swizzled (T2).
// Staging ledger (per wave): during tile t issue B(t+2)h0 (ph1, 2 ops),
// B(t+2)h1 (ph2, 2), A(t+2) (ph3, 4). At ph2-end in-flight = t+1's 8 +
// t+2's B 4 -> vmcnt(4) drains exactly tile t+1 => ph3 may register-prefetch
// Q0/b0 of tile t+1 from slot d^1. Reads/phase: 10/4/4/6 (was 16/4/4/0).
// ---------------------------------------------------------------------------
__device__ __forceinline__ f32x4 mfma16(bf16x8 a, bf16x8 b, f32x4 c) {
    return __builtin_amdgcn_mfma_f32_16x16x32_bf16(a, b, c, 0, 0, 0);
}

#define MFMAQ(Q, A00, A01, A10, A11)                                        \
    __builtin_amdgcn_s_setprio(1);                                          \
    _Pragma("unroll")                                                       \
    for (int n = 0; n < 4; ++n) {                                           \
        acc[2*(Q)][n]   = mfma16(A00, bb[n][0], acc[2*(Q)][n]);             \
        acc[2*(Q)][n]   = mfma16(A01, bb[n][1], acc[2*(Q)][n]);             \
        acc[2*(Q)+1][n] = mfma16(A10, bb[n][0], acc[2*(Q)+1][n]);           \
        acc[2*(Q)+1][n] = mfma16(A11, bb[n][1], acc[2*(Q)+1][n]);           \
    }                                                                       \
    __builtin_amdgcn_s_setprio(0);

#define BAR()   __builtin_amdgcn_s_barrier(); __builtin_amdgcn_sched_barrier(0)
#define LGKM0() asm volatile("s_waitcnt lgkmcnt(0)" ::: "memory")
#define VM8()   asm volatile("s_waitcnt vmcnt(8)" ::: "memory")
#define VM4()   asm volatile("s_waitcnt vmcnt(4)" ::: "memory")
#define VM0()   asm volatile("s_waitcnt vmcnt(0)" ::: "memory")

template<bool F32OUT>
__global__ __launch_bounds__(512, 2) void gemm8p(
    const __bf16* __restrict__ A, const __bf16* __restrict__ W,
    const float* __restrict__ bias,
    __bf16* __restrict__ outb, float* __restrict__ outf) {
    constexpr int NT = 16;  // K/64
    extern __shared__ char smem[];  // A: [0,64K), B: [64K,128K)

    const int t   = threadIdx.x;
    const int l   = t & 63, l15 = l & 15, lhi = l >> 4;
    const int w   = t >> 6, wr = w >> 2, wc = w & 3;

    // T1: bijective XCD swizzle (256 blocks, 8 XCDs)
    const int bid = blockIdx.x;
    const int swz = (bid & 7) * 32 + (bid >> 3);
    const int bx = swz & 3, by = swz >> 2;
    const int brow = by * 256, bcol = bx * 256;

    // staging consts: row = t>>3, in-row 16B block (t&7) XOR'd by row&7 (T2).
    const int srow = t >> 3;
    const int scol = (((t & 7) ^ ((t >> 3) & 7)) << 4) >> 1;
    const __bf16* gA = A + (size_t)(brow + srow) * 1024 + scol;
    const __bf16* gW = W + (size_t)(bcol + srow) * 1024 + scol;
    const int woff = (t & 448) * 16;  // wave*1024 (wave-uniform)

    char* const ldsA = smem;
    char* const ldsB = smem + 65536;

    auto stageAfull = [&](int d, int k0) {  // 4 ops: 256 rows x 64k
        const __bf16* g = gA + k0;
        char* p = ldsA + d * 32768 + woff;
        gload_lds16(g,          p);
        gload_lds16(g + 65536,  p + 8192);
        gload_lds16(g + 131072, p + 16384);
        gload_lds16(g + 196608, p + 24576);
    };
    auto stageBh = [&](int d, int h, int k0) {  // 2 ops: 128 rows x 64k
        const __bf16* g = gW + (size_t)h * 131072 + k0;
        char* p = ldsB + d * 32768 + h * 16384 + woff;
        gload_lds16(g, p);
        gload_lds16(g + 65536, p + 8192);
    };

    // fragment-read consts (T2 swizzled)
    const int xorm  = (l & 7) << 4;
    const int koff0 = (lhi * 16) ^ xorm;
    const int koff1 = (64 + lhi * 16) ^ xorm;
    char* const aBase = ldsA + wr * 16384 + l15 * 128;
    char* const bBase = ldsB + wc * 8192 + l15 * 128;

    f32x4 acc[8][4] = {};
    bf16x8 bb[4][2], bp0, bp1;
    bf16x8 a00, a01, a10, a11, c00, c01, c10, c11;

    // prologue: stage tiles 0,1 (16 ops); keep tile1's 8 in flight
    stageAfull(0, 0);  stageBh(0, 0, 0);  stageBh(0, 1, 0);
    stageAfull(1, 64); stageBh(1, 0, 64); stageBh(1, 1, 64);
    VM8(); BAR();
    // pre-read tile0 Q0 A-frags + b[0] pair
    a00 = *(const bf16x8*)(aBase + 0 * 2048 + koff0);
    a01 = *(const bf16x8*)(aBase + 0 * 2048 + koff1);
    a10 = *(const bf16x8*)(aBase + 1 * 2048 + koff0);
    a11 = *(const bf16x8*)(aBase + 1 * 2048 + koff1);
    bp0 = *(const bf16x8*)(bBase + koff0);
    bp1 = *(const bf16x8*)(bBase + koff1);

    #pragma unroll 2
    for (int tt = 0; tt < NT; ++tt) {
        const int d  = tt & 1;
        const int k2 = (tt + 2) * 64;
        char* const aB  = aBase + d * 32768;
        char* const bB  = bBase + d * 32768;
        char* const aBn = aBase + (d ^ 1) * 32768;
        char* const bBn = bBase + (d ^ 1) * 32768;
        const bool st = (tt + 2 < NT);
        const bool pf = (tt + 1 < NT);

        // ---- ph0: b[1..3] + Q1 reads; MFMA Q0 (fully prefetched) ----
        bb[0][0] = bp0; bb[0][1] = bp1;
        bb[1][0] = *(const bf16x8*)(bB + 1 * 2048 + koff0);
        bb[1][1] = *(const bf16x8*)(bB + 1 * 2048 + koff1);
        bb[2][0] = *(const bf16x8*)(bB + 2 * 2048 + koff0);
        bb[2][1] = *(const bf16x8*)(bB + 2 * 2048 + koff1);
        bb[3][0] = *(const bf16x8*)(bB + 3 * 2048 + koff0);
        bb[3][1] = *(const bf16x8*)(bB + 3 * 2048 + koff1);
        c00 = *(const bf16x8*)(aB + 2 * 2048 + koff0);
        c01 = *(const bf16x8*)(aB + 2 * 2048 + koff1);
        c10 = *(const bf16x8*)(aB + 3 * 2048 + koff0);
        c11 = *(const bf16x8*)(aB + 3 * 2048 + koff1);
        MFMAQ(0, a00, a01, a10, a11);
        LGKM0(); BAR();

        // ---- ph1: stage B(t+2)h0; read Q2; MFMA Q1 ----
        if (st) stageBh(d, 0, k2);
        a00 = *(const bf16x8*)(aB + 4 * 2048 + koff0);
        a01 = *(const bf16x8*)(aB + 4 * 2048 + koff1);
        a10 = *(const bf16x8*)(aB + 5 * 2048 + koff0);
        a11 = *(const bf16x8*)(aB + 5 * 2048 + koff1);
        MFMAQ(1, c00, c01, c10, c11);
        LGKM0(); BAR();

        // ---- ph2: stage B(t+2)h1; read Q3; MFMA Q2; boundary vmcnt ----
        if (st) stageBh(d, 1, k2);
        c00 = *(const bf16x8*)(aB + 6 * 2048 + koff0);
        c01 = *(const bf16x8*)(aB + 6 * 2048 + koff1);
        c10 = *(const bf16x8*)(aB + 7 * 2048 + koff0);
        c11 = *(const bf16x8*)(aB + 7 * 2048 + koff1);
        MFMAQ(2, a00, a01, a10, a11);
        if (tt <= NT - 3)      { VM4(); }   // drain t+1's 8, keep t+2's B 4
        else if (tt == NT - 2) { VM0(); }
        LGKM0(); BAR();

        // ---- ph3: stage A(t+2); prefetch Q0/b0 of tile t+1; MFMA Q3 ----
        if (st) stageAfull(d, k2);
        if (pf) {
            a00 = *(const bf16x8*)(aBn + 0 * 2048 + koff0);
            a01 = *(const bf16x8*)(aBn + 0 * 2048 + koff1);
            a10 = *(const bf16x8*)(aBn + 1 * 2048 + koff0);
            a11 = *(const bf16x8*)(aBn + 1 * 2048 + koff1);
            bp0 = *(const bf16x8*)(bBn + koff0);
            bp1 = *(const bf16x8*)(bBn + koff1);
        }
        MFMAQ(3, c00, c01, c10, c11);
        LGKM0(); BAR();
    }

    // ---- epilogue ----
    if constexpr (F32OUT) {
        // restage through LDS in two 128-row chunks -> dwordx4 stores
        char* const cl = smem;
        #pragma unroll
        for (int chunk = 0; chunk < 2; ++chunk) {
            __syncthreads();
            if (wr == chunk) {
                #pragma unroll
                for (int n = 0; n < 4; ++n) {
                    const int colb = (wc * 64 + n * 16 + l15) * 4;
                    const float bv = bias[bcol + wc * 64 + n * 16 + l15];
                    #pragma unroll
                    for (int m = 0; m < 8; ++m) {
                        #pragma unroll
                        for (int r = 0; r < 4; ++r) {
                            const int row = m * 16 + lhi * 4 + r;
                            float v = acc[m][n][r] + bv;
                            v = v > 0.f ? v : 0.f;
                            *(float*)(cl + row * 1024 + (colb ^ ((row & 12) << 4))) = v;
                        }
                    }
                }
            }
            __syncthreads();
            #pragma unroll
            for (int rd = 0; rd < 16; ++rd) {
                const int off = rd * 8192 + t * 16;
                const int row = off >> 10;
                const int cb  = (off & 1023) ^ ((row & 12) << 4);
                float4 v = *(const float4*)(cl + off);
                *(float4*)((char*)outf +
                           ((size_t)(brow + chunk * 128 + row) * 1024 + bcol) * 4 + cb) = v;
            }
        }
    } else {
        // restage C tile (256x256 bf16 = 128K) in LDS, then coalesced stores
        __syncthreads();
        char* const cl = smem;
        #pragma unroll
        for (int n = 0; n < 4; ++n) {
            const int colb = (wc * 64 + n * 16 + l15) * 2;
            const float bv = bias[bcol + wc * 64 + n * 16 + l15];
            #pragma unroll
            for (int m = 0; m < 8; ++m) {
                #pragma unroll
                for (int r = 0; r < 4; ++r) {
                    const int row = wr * 128 + m * 16 + lhi * 4 + r;
                    float v = acc[m][n][r] + bv;
                    v = v > 0.f ? v : 0.f;
                    *(__bf16*)(cl + row * 512 + (colb ^ ((row & 12) << 3))) = (__bf16)v;
                }
            }
        }
        __syncthreads();
        #pragma unroll
        for (int rd = 0; rd < 16; ++rd) {
            const int off = rd * 8192 + t * 16;
            const int row = off >> 9;
            const int cb  = (off & 511) ^ ((row & 12) << 3);
            bf16x8 v = *(const bf16x8*)(cl + off);
            *(bf16x8*)((char*)outb + ((size_t)(brow + row) * 1024 + bcol) * 2 + cb) = v;
        }
    }
}

// ---------------------------------------------------------------------------
extern "C" void kernel_launch(void* const* d_in, const int* in_sizes, int n_in,
                              void* d_out, int out_size, void* d_ws, size_t ws_size,
                              hipStream_t stream) {
    const float* x  = (const float*)d_in[0];
    const float* w0 = (const float*)d_in[1];
    const float* b0 = (const float*)d_in[2];
    const float* w1 = (const float*)d_in[3];
    const float* b1 = (const float*)d_in[4];
    const void*  m1 = d_in[5];
    const float* w2 = (const float*)d_in[6];
    const float* b2 = (const float*)d_in[7];
    const void*  m2 = d_in[8];
    float* out = (float*)d_out;

    char* ws = (char*)d_ws;
    __bf16* xb  = (__bf16*)(ws);                             // 32 MiB (x, later h2)
    __bf16* h1  = (__bf16*)(ws + (size_t)32 * 1024 * 1024);  // 32 MiB
    __bf16* w0b = (__bf16*)(ws + (size_t)64 * 1024 * 1024);
    __bf16* w1b = w0b + 1024 * 1024;
    __bf16* w2b = w1b + 1024 * 1024;
    int*   flag = (int*)(w2b + 1024 * 1024);

    hipFuncSetAttribute((const void*)gemm8p<false>,
                        hipFuncAttributeMaxDynamicSharedMemorySize, 131072);
    hipFuncSetAttribute((const void*)gemm8p<true>,
                        hipFuncAttributeMaxDynamicSharedMemorySize, 131072);

    detect_mask<<<1, 64, 0, stream>>>((const unsigned char*)m1, flag);
    prep_all<<<9728, 256, 0, stream>>>(x, xb, w0, w1, w2, m1, m2, flag,
                                       w0b, w1b, w2b);

    gemm8p<false><<<256, 512, 131072, stream>>>(xb, w0b, b0, h1, nullptr);
    gemm8p<false><<<256, 512, 131072, stream>>>(h1, w1b, b1, xb, nullptr);  // h2 -> xb
    gemm8p<true ><<<256, 512, 131072, stream>>>(xb, w2b, b2, nullptr, out);
}

// Round 5
// 129.958 us; speedup vs baseline: 1.0043x; 1.0043x over previous
//
#include <hip/hip_runtime.h>
#include <hip/hip_bf16.h>
#include <cstdint>
#include <cstddef>

// ---------------------------------------------------------------------------
// ThreeLayerFCModel: out = relu(relu(relu(x@w0^T+b0)@(w1*m1)^T+b1)@(w2*m2)^T+b2)
// B=16384, dims 1024. Round 5: round-3 schedule (best so far) with
// sched_barrier(0) REMOVED from the phase loop (m141: order-pinning defeats
// the compiler scheduler); f32 epilogue LDS-restaged (round-4, WRITE=ideal).
// ---------------------------------------------------------------------------

typedef __bf16 bf16x8 __attribute__((ext_vector_type(8)));
typedef float  f32x4  __attribute__((ext_vector_type(4)));

#define AS1 __attribute__((address_space(1)))
#define AS3 __attribute__((address_space(3)))

__device__ __forceinline__ void gload_lds16(const void* g, void* l) {
    __builtin_amdgcn_global_load_lds((const AS1 void*)g, (AS3 void*)l, 16, 0, 0);
}

// ---------------- mask dtype detection (uint8 / int32 / f32) ----------------
__global__ void detect_mask(const unsigned char* __restrict__ m, int* __restrict__ flag) {
    const int t = threadIdx.x;  // 64
    int or1 = 0, or3 = 0;
    for (int e = t; e < 256; e += 64) { or1 |= m[e * 4 + 1]; or3 |= m[e * 4 + 3]; }
    unsigned long long b1 = __ballot(or1 != 0);
    unsigned long long b3 = __ballot(or3 != 0);
    if (t == 0) *flag = b1 ? 1 : (b3 ? 2 : 0);
}

// ---------------- fused prep: cvt x->bf16 + 3x (w*mask)->bf16 ---------------
__device__ __forceinline__ void prep_body(const float* __restrict__ w,
                                          const void* __restrict__ mask, int mode,
                                          __bf16* __restrict__ out, long i) {
    float4 a = *reinterpret_cast<const float4*>(w + i);
    float4 b = *reinterpret_cast<const float4*>(w + i + 4);
    float v[8] = {a.x, a.y, a.z, a.w, b.x, b.y, b.z, b.w};
    if (mask) {
        if (mode == 1) {
            const unsigned char* mp = (const unsigned char*)mask;
            #pragma unroll
            for (int j = 0; j < 8; ++j) v[j] = mp[i + j] ? v[j] : 0.f;
        } else if (mode == 0) {
            const int* mp = (const int*)mask;
            #pragma unroll
            for (int j = 0; j < 8; ++j) v[j] = mp[i + j] ? v[j] : 0.f;
        } else {
            const float* mp = (const float*)mask;
            #pragma unroll
            for (int j = 0; j < 8; ++j) v[j] = (mp[i + j] != 0.f) ? v[j] : 0.f;
        }
    }
    bf16x8 o;
    #pragma unroll
    for (int j = 0; j < 8; ++j) o[j] = (__bf16)v[j];
    *reinterpret_cast<bf16x8*>(out + i) = o;
}

__global__ void prep_all(const float* __restrict__ x, __bf16* __restrict__ xb,
                         const float* __restrict__ w0, const float* __restrict__ w1,
                         const float* __restrict__ w2,
                         const void* __restrict__ m1, const void* __restrict__ m2,
                         const int* __restrict__ flag,
                         __bf16* __restrict__ w0b, __bf16* __restrict__ w1b,
                         __bf16* __restrict__ w2b) {
    const int bid = blockIdx.x;
    if (bid < 8192) {  // x -> bf16 (16M elems)
        long i = ((long)bid * blockDim.x + threadIdx.x) * 8;
        float4 a = *reinterpret_cast<const float4*>(x + i);
        float4 b = *reinterpret_cast<const float4*>(x + i + 4);
        bf16x8 o;
        o[0] = (__bf16)a.x; o[1] = (__bf16)a.y; o[2] = (__bf16)a.z; o[3] = (__bf16)a.w;
        o[4] = (__bf16)b.x; o[5] = (__bf16)b.y; o[6] = (__bf16)b.z; o[7] = (__bf16)b.w;
        *reinterpret_cast<bf16x8*>(xb + i) = o;
    } else {
        const int q = bid - 8192, wi = q >> 9, sub = q & 511;
        long i = ((long)sub * blockDim.x + threadIdx.x) * 8;
        const int mode = *flag;
        if (wi == 0)      prep_body(w0, nullptr, mode, w0b, i);
        else if (wi == 1) prep_body(w1, m1,      mode, w1b, i);
        else              prep_body(w2, m2,      mode, w2b, i);
    }
}

// ---------------------------------------------------------------------------
// 256x256-tile GEMM: C = relu(A[16384,1024] * W[1024,1024]^T + bias)
// 512 thr = 8 waves (2 row x 4 col), per-wave 128x64 out, BK=64, 16 K-tiles.
// LDS 128 KiB: A/B each [2 dbuf][256 rows][64 k] bf16, XOR-swizzled (T2).
// Schedule (round-3): ph0 reads B[0..3]+Q0+Q1 then MFMA Q0; ph1 stage
// B(t+2)h0, read Q2, MFMA Q1; ph2 stage B(t+2)h1, read Q3, MFMA Q2;
// ph3 stage A(t+2), MFMA Q3, boundary vmcnt(8). NO sched_barrier pinning.
// ---------------------------------------------------------------------------
__device__ __forceinline__ f32x4 mfma16(bf16x8 a, bf16x8 b, f32x4 c) {
    return __builtin_amdgcn_mfma_f32_16x16x32_bf16(a, b, c, 0, 0, 0);
}

#define MFMAQ(Q, A00, A01, A10, A11)                                        \
    __builtin_amdgcn_s_setprio(1);                                          \
    _Pragma("unroll")                                                       \
    for (int n = 0; n < 4; ++n) {                                           \
        acc[2*(Q)][n]   = mfma16(A00, b[n][0], acc[2*(Q)][n]);              \
        acc[2*(Q)][n]   = mfma16(A01, b[n][1], acc[2*(Q)][n]);              \
        acc[2*(Q)+1][n] = mfma16(A10, b[n][0], acc[2*(Q)+1][n]);            \
        acc[2*(Q)+1][n] = mfma16(A11, b[n][1], acc[2*(Q)+1][n]);            \
    }                                                                       \
    __builtin_amdgcn_s_setprio(0);

#define BAR()   __builtin_amdgcn_s_barrier()
#define LGKM0() asm volatile("s_waitcnt lgkmcnt(0)" ::: "memory")
#define VM8()   asm volatile("s_waitcnt vmcnt(8)" ::: "memory")
#define VM0()   asm volatile("s_waitcnt vmcnt(0)" ::: "memory")

template<bool F32OUT>
__global__ __launch_bounds__(512, 2) void gemm8p(
    const __bf16* __restrict__ A, const __bf16* __restrict__ W,
    const float* __restrict__ bias,
    __bf16* __restrict__ outb, float* __restrict__ outf) {
    constexpr int NT = 16;  // K/64
    extern __shared__ char smem[];  // A: [0,64K), B: [64K,128K)

    const int t   = threadIdx.x;
    const int l   = t & 63, l15 = l & 15, lhi = l >> 4;
    const int w   = t >> 6, wr = w >> 2, wc = w & 3;

    // T1: bijective XCD swizzle (256 blocks, 8 XCDs)
    const int bid = blockIdx.x;
    const int swz = (bid & 7) * 32 + (bid >> 3);
    const int bx = swz & 3, by = swz >> 2;
    const int brow = by * 256, bcol = bx * 256;

    // staging consts: row = t>>3, in-row 16B block (t&7) XOR'd by row&7 (T2).
    const int srow = t >> 3;
    const int scol = (((t & 7) ^ ((t >> 3) & 7)) << 4) >> 1;
    const __bf16* gA = A + (size_t)(brow + srow) * 1024 + scol;
    const __bf16* gW = W + (size_t)(bcol + srow) * 1024 + scol;
    const int woff = (t & 448) * 16;  // wave*1024 (wave-uniform)

    char* const ldsA = smem;
    char* const ldsB = smem + 65536;

    auto stageAfull = [&](int d, int k0) {  // 4 ops: 256 rows x 64k
        const __bf16* g = gA + k0;
        char* p = ldsA + d * 32768 + woff;
        gload_lds16(g,          p);
        gload_lds16(g + 65536,  p + 8192);
        gload_lds16(g + 131072, p + 16384);
        gload_lds16(g + 196608, p + 24576);
    };
    auto stageBh = [&](int d, int h, int k0) {  // 2 ops: 128 rows x 64k
        const __bf16* g = gW + (size_t)h * 131072 + k0;
        char* p = ldsB + d * 32768 + h * 16384 + woff;
        gload_lds16(g, p);
        gload_lds16(g + 65536, p + 8192);
    };

    // fragment-read consts (T2 swizzled)
    const int xorm  = (l & 7) << 4;
    const int koff0 = (lhi * 16) ^ xorm;
    const int koff1 = (64 + lhi * 16) ^ xorm;
    char* const aBase = ldsA + wr * 16384 + l15 * 128;
    char* const bBase = ldsB + wc * 8192 + l15 * 128;

    f32x4 acc[8][4] = {};

    // prologue: stage tiles 0,1 (16 ops); keep tile1's 8 in flight
    stageAfull(0, 0);  stageBh(0, 0, 0);  stageBh(0, 1, 0);
    stageAfull(1, 64); stageBh(1, 0, 64); stageBh(1, 1, 64);
    VM8(); BAR();

    #pragma unroll 2
    for (int tt = 0; tt < NT; ++tt) {
        const int d  = tt & 1;
        const int k2 = (tt + 2) * 64;
        char* const aB = aBase + d * 32768;
        char* const bB = bBase + d * 32768;
        const bool st = (tt + 2 < NT);

        // ---- ph0: read all B frags + A Q0,Q1 frags; MFMA Q0 ----
        bf16x8 b[4][2];
        #pragma unroll
        for (int n = 0; n < 4; ++n) {
            b[n][0] = *(const bf16x8*)(bB + n * 2048 + koff0);
            b[n][1] = *(const bf16x8*)(bB + n * 2048 + koff1);
        }
        bf16x8 a00 = *(const bf16x8*)(aB + 0 * 2048 + koff0);
        bf16x8 a01 = *(const bf16x8*)(aB + 0 * 2048 + koff1);
        bf16x8 a10 = *(const bf16x8*)(aB + 1 * 2048 + koff0);
        bf16x8 a11 = *(const bf16x8*)(aB + 1 * 2048 + koff1);
        bf16x8 c00 = *(const bf16x8*)(aB + 2 * 2048 + koff0);
        bf16x8 c01 = *(const bf16x8*)(aB + 2 * 2048 + koff1);
        bf16x8 c10 = *(const bf16x8*)(aB + 3 * 2048 + koff0);
        bf16x8 c11 = *(const bf16x8*)(aB + 3 * 2048 + koff1);
        MFMAQ(0, a00, a01, a10, a11);
        LGKM0(); BAR();

        // ---- ph1: stage B(t+2)h0; read Q2; MFMA Q1 ----
        if (st) stageBh(d, 0, k2);
        a00 = *(const bf16x8*)(aB + 4 * 2048 + koff0);
        a01 = *(const bf16x8*)(aB + 4 * 2048 + koff1);
        a10 = *(const bf16x8*)(aB + 5 * 2048 + koff0);
        a11 = *(const bf16x8*)(aB + 5 * 2048 + koff1);
        MFMAQ(1, c00, c01, c10, c11);
        LGKM0(); BAR();

        // ---- ph2: stage B(t+2)h1; read Q3; MFMA Q2 ----
        if (st) stageBh(d, 1, k2);
        c00 = *(const bf16x8*)(aB + 6 * 2048 + koff0);
        c01 = *(const bf16x8*)(aB + 6 * 2048 + koff1);
        c10 = *(const bf16x8*)(aB + 7 * 2048 + koff0);
        c11 = *(const bf16x8*)(aB + 7 * 2048 + koff1);
        MFMAQ(2, a00, a01, a10, a11);
        LGKM0(); BAR();

        // ---- ph3: stage A(t+2); MFMA Q3; counted boundary wait ----
        if (st) stageAfull(d, k2);
        MFMAQ(3, c00, c01, c10, c11);
        if (tt <= NT - 3)      { VM8(); BAR(); }
        else if (tt == NT - 2) { VM0(); BAR(); }
    }

    // ---- epilogue ----
    if constexpr (F32OUT) {
        // restage through LDS in two 128-row chunks -> coalesced dwordx4
        char* const cl = smem;
        #pragma unroll
        for (int chunk = 0; chunk < 2; ++chunk) {
            __syncthreads();
            if (wr == chunk) {
                #pragma unroll
                for (int n = 0; n < 4; ++n) {
                    const int colb = (wc * 64 + n * 16 + l15) * 4;
                    const float bv = bias[bcol + wc * 64 + n * 16 + l15];
                    #pragma unroll
                    for (int m = 0; m < 8; ++m) {
                        #pragma unroll
                        for (int r = 0; r < 4; ++r) {
                            const int row = m * 16 + lhi * 4 + r;
                            float v = acc[m][n][r] + bv;
                            v = v > 0.f ? v : 0.f;
                            *(float*)(cl + row * 1024 + (colb ^ ((row & 12) << 4))) = v;
                        }
                    }
                }
            }
            __syncthreads();
            #pragma unroll
            for (int rd = 0; rd < 16; ++rd) {
                const int off = rd * 8192 + t * 16;
                const int row = off >> 10;
                const int cb  = (off & 1023) ^ ((row & 12) << 4);
                float4 v = *(const float4*)(cl + off);
                *(float4*)((char*)outf +
                           ((size_t)(brow + chunk * 128 + row) * 1024 + bcol) * 4 + cb) = v;
            }
        }
    } else {
        // restage C tile (256x256 bf16 = 128K) in LDS, then coalesced stores
        __syncthreads();
        char* const cl = smem;
        #pragma unroll
        for (int n = 0; n < 4; ++n) {
            const int colb = (wc * 64 + n * 16 + l15) * 2;
            const float bv = bias[bcol + wc * 64 + n * 16 + l15];
            #pragma unroll
            for (int m = 0; m < 8; ++m) {
                #pragma unroll
                for (int r = 0; r < 4; ++r) {
                    const int row = wr * 128 + m * 16 + lhi * 4 + r;
                    float v = acc[m][n][r] + bv;
                    v = v > 0.f ? v : 0.f;
                    *(__bf16*)(cl + row * 512 + (colb ^ ((row & 12) << 3))) = (__bf16)v;
                }
            }
        }
        __syncthreads();
        #pragma unroll
        for (int rd = 0; rd < 16; ++rd) {
            const int off = rd * 8192 + t * 16;
            const int row = off >> 9;
            const int cb  = (off & 511) ^ ((row & 12) << 3);
            bf16x8 v = *(const bf16x8*)(cl + off);
            *(bf16x8*)((char*)outb + ((size_t)(brow + row) * 1024 + bcol) * 2 + cb) = v;
        }
    }
}

// ---------------------------------------------------------------------------
extern "C" void kernel_launch(void* const* d_in, const int* in_sizes, int n_in,
                              void* d_out, int out_size, void* d_ws, size_t ws_size,
                              hipStream_t stream) {
    const float* x  = (const float*)d_in[0];
    const float* w0 = (const float*)d_in[1];
    const float* b0 = (const float*)d_in[2];
    const float* w1 = (const float*)d_in[3];
    const float* b1 = (const float*)d_in[4];
    const void*  m1 = d_in[5];
    const float* w2 = (const float*)d_in[6];
    const float* b2 = (const float*)d_in[7];
    const void*  m2 = d_in[8];
    float* out = (float*)d_out;

    char* ws = (char*)d_ws;
    __bf16* xb  = (__bf16*)(ws);                             // 32 MiB (x, later h2)
    __bf16* h1  = (__bf16*)(ws + (size_t)32 * 1024 * 1024);  // 32 MiB
    __bf16* w0b = (__bf16*)(ws + (size_t)64 * 1024 * 1024);
    __bf16* w1b = w0b + 1024 * 1024;
    __bf16* w2b = w1b + 1024 * 1024;
    int*   flag = (int*)(w2b + 1024 * 1024);

    hipFuncSetAttribute((const void*)gemm8p<false>,
                        hipFuncAttributeMaxDynamicSharedMemorySize, 131072);
    hipFuncSetAttribute((const void*)gemm8p<true>,
                        hipFuncAttributeMaxDynamicSharedMemorySize, 131072);

    detect_mask<<<1, 64, 0, stream>>>((const unsigned char*)m1, flag);
    prep_all<<<9728, 256, 0, stream>>>(x, xb, w0, w1, w2, m1, m2, flag,
                                       w0b, w1b, w2b);

    gemm8p<false><<<256, 512, 131072, stream>>>(xb, w0b, b0, h1, nullptr);
    gemm8p<false><<<256, 512, 131072, stream>>>(h1, w1b, b1, xb, nullptr);  // h2 -> xb
    gemm8p<true ><<<256, 512, 131072, stream>>>(xb, w2b, b2, nullptr, out);
}